// Round 2
// baseline (292.747 us; speedup 1.0000x reference)
//
#include <hip/hip_runtime.h>

#define Hh 96
#define Ww 96
#define CIN 64
#define COUT 64
#define BATCH 8
#define HW 9216           // Hh*Ww
#define NOFF 18           // 2*K*K

typedef __attribute__((ext_vector_type(8))) short bf16x8;
typedef __attribute__((ext_vector_type(4))) float f32x4;

__device__ inline ushort f2bf(float f) {
  union { float f; uint u; } v; v.f = f;
  uint u = v.u;
  u += 0x7FFF + ((u >> 16) & 1);     // RNE
  return (ushort)(u >> 16);
}

// ---------------------------------------------------------------------------
// K1: offset conv (18 channels, 3x3, pad 1) + fold w_def -> bf16 [k][o][c].
// ---------------------------------------------------------------------------
__global__ __launch_bounds__(256) void k_offset(
    const float* __restrict__ x, const float* __restrict__ w_off,
    const float* __restrict__ b_off, const float* __restrict__ w_def,
    float* __restrict__ offs, ushort* __restrict__ wtb)
{
  __shared__ float wl[CIN * 9 * 20];       // [c][kk][j padded to 20]
  __shared__ float red[3 * NOFF * 64];

  int tid = threadIdx.x;
  int blk = blockIdx.x;

  // one-time transpose w_def[o][c][k] -> wtb[k][o][c] (bf16)
  if (blk < 144) {
    int g = blk * 256 + tid;
    int k = g >> 12, o = (g >> 6) & 63, c = g & 63;
    wtb[g] = f2bf(w_def[(o * 64 + c) * 9 + k]);
  }

  for (int i = tid; i < NOFF * CIN * 9; i += 256) {
    int j = i / 576;
    int rem = i - j * 576;
    int c = rem / 9;
    int kk = rem - c * 9;
    wl[(c * 9 + kk) * 20 + j] = w_off[i];
  }
  __syncthreads();

  int wave = tid >> 6, lane = tid & 63;
  int p = blk * 64 + lane;
  int b = p / HW;
  int pp = p - b * HW;
  int h = pp / Ww;
  int w = pp - h * Ww;

  float acc[NOFF];
  #pragma unroll
  for (int j = 0; j < NOFF; ++j) acc[j] = 0.f;

  int woff[9];
  float okf[9];
  #pragma unroll
  for (int kk = 0; kk < 9; ++kk) {
    int yy = h + kk / 3 - 1, xx = w + (kk % 3) - 1;
    bool ok = (yy >= 0 && yy < Hh && xx >= 0 && xx < Ww);
    int yc = min(max(yy, 0), Hh - 1), xc = min(max(xx, 0), Ww - 1);
    woff[kk] = yc * Ww + xc;
    okf[kk] = ok ? 1.f : 0.f;
  }

  const float* xb = x + (size_t)(b * CIN + wave * 16) * HW;
  for (int ci = 0; ci < 16; ++ci) {
    const float* xc = xb + ci * HW;
    int c = wave * 16 + ci;
    float xv[9];
    #pragma unroll
    for (int kk = 0; kk < 9; ++kk) xv[kk] = xc[woff[kk]] * okf[kk];
    const float* wr = &wl[c * 180];
    #pragma unroll
    for (int kk = 0; kk < 9; ++kk) {
      const float* wj = wr + kk * 20;
      #pragma unroll
      for (int j = 0; j < NOFF; ++j)
        acc[j] = fmaf(xv[kk], wj[j], acc[j]);
    }
  }

  if (wave > 0) {
    #pragma unroll
    for (int j = 0; j < NOFF; ++j)
      red[(wave - 1) * NOFF * 64 + j * 64 + lane] = acc[j];
  }
  __syncthreads();
  if (wave == 0) {
    #pragma unroll
    for (int j = 0; j < NOFF; ++j) {
      float a = acc[j] + red[j * 64 + lane] + red[1152 + j * 64 + lane] +
                red[2304 + j * 64 + lane];
      offs[((size_t)b * NOFF + j) * HW + pp] = a + b_off[j];
    }
  }
}

// ---------------------------------------------------------------------------
// K2: deformable sampling + MFMA contraction + fused BN partial sums.
// Block = 256 threads (4 waves), 64 pixels x 64 outputs.
// Wave w computes pixels [16w,16w+16) x all 64 outputs (4 MFMA N-tiles).
// K-order: kk-major then c (any consistent bijection is valid since both
// operands are packed by us; C/D layout is the HW-verified one).
// ---------------------------------------------------------------------------
__global__ __launch_bounds__(256) void k_deform(
    const float* __restrict__ x, const float* __restrict__ offs,
    const ushort* __restrict__ wtb, const float* __restrict__ b_def,
    float* __restrict__ out, float* __restrict__ parts)
{
  __shared__ float lds_f[4416];     // S: [c][p] stride 69 | epilogue Of: [o][p] stride 68
  __shared__ ushort Wl[64 * 72];    // [o][c] stride 72 (bf16)
  __shared__ float red[512];

  int tid = threadIdx.x;
  int blk = blockIdx.x;             // 1152 = 8 * 144
  int b = blk / 144;
  int pbase = (blk - b * 144) * 64;
  int wave = tid >> 6, lane = tid & 63;
  int p = pbase + lane;
  int h = p / Ww, w = p - h * Ww;
  int m = lane & 15, hi = lane >> 4;

  f32x4 acc[4];
  #pragma unroll
  for (int nt = 0; nt < 4; ++nt) acc[nt] = (f32x4){0.f, 0.f, 0.f, 0.f};

  float bdv[4];
  #pragma unroll
  for (int nt = 0; nt < 4; ++nt) bdv[nt] = b_def[nt * 16 + m];

  const float* xb = x + (size_t)(b * CIN + wave * 16) * HW;

  for (int k = 0; k < 9; ++k) {
    // stage Wk[o][c] bf16 (4096 elems) -> Wl stride 72
    {
      const uint4* src = (const uint4*)(wtb + (size_t)k * 4096);
      #pragma unroll
      for (int i = 0; i < 2; ++i) {
        int g = tid + i * 256;
        int o = g >> 3, c8 = (g & 7) * 8;
        *(uint4*)&Wl[o * 72 + c8] = src[g];
      }
    }

    // bilinear sampling: wave handles channels [16w,16w+16), lane = pixel
    float dy = offs[((size_t)b * NOFF + 2 * k) * HW + p];
    float dx = offs[((size_t)b * NOFF + 2 * k + 1) * HW + p];
    float py = (float)(h + k / 3 - 1) + dy;
    float px = (float)(w + (k % 3) - 1) + dx;
    float y0f = floorf(py), x0f = floorf(px);
    float ly = py - y0f, lx = px - x0f;
    int y0 = (int)y0f, x0 = (int)x0f;
    int y1 = y0 + 1, x1 = x0 + 1;
    float wy0 = 1.f - ly, wy1 = ly, wx0 = 1.f - lx, wx1 = lx;
    float fy0 = (y0 >= 0 && y0 < Hh) ? 1.f : 0.f;
    float fy1 = (y1 >= 0 && y1 < Hh) ? 1.f : 0.f;
    float fx0 = (x0 >= 0 && x0 < Ww) ? 1.f : 0.f;
    float fx1 = (x1 >= 0 && x1 < Ww) ? 1.f : 0.f;
    int cy0 = min(max(y0, 0), Hh - 1), cy1 = min(max(y1, 0), Hh - 1);
    int cx0 = min(max(x0, 0), Ww - 1), cx1 = min(max(x1, 0), Ww - 1);
    int o00 = cy0 * Ww + cx0, o01 = cy0 * Ww + cx1;
    int o10 = cy1 * Ww + cx0, o11 = cy1 * Ww + cx1;
    float w00 = (wy0 * wx0) * (fy0 * fx0);
    float w01 = (wy0 * wx1) * (fy0 * fx1);
    float w10 = (wy1 * wx0) * (fy1 * fx0);
    float w11 = (wy1 * wx1) * (fy1 * fx1);

    #pragma unroll
    for (int ci = 0; ci < 16; ++ci) {
      const float* xc = xb + ci * HW;
      float v = w00 * xc[o00] + w01 * xc[o01] + w10 * xc[o10] + w11 * xc[o11];
      lds_f[(wave * 16 + ci) * 69 + lane] = v;
    }
    __syncthreads();

    // A-frags: pixel column (16*wave + m), 8 consecutive c-rows per half
    bf16x8 a0, a1;
    {
      const float* Sb = lds_f + 16 * wave + m;
      #pragma unroll
      for (int j = 0; j < 8; ++j) {
        a0[j] = (short)f2bf(Sb[(hi * 8 + j) * 69]);
        a1[j] = (short)f2bf(Sb[(32 + hi * 8 + j) * 69]);
      }
    }

    #pragma unroll
    for (int nt = 0; nt < 4; ++nt) {
      const ushort* wr = &Wl[(nt * 16 + m) * 72 + hi * 8];
      bf16x8 b0 = *(const bf16x8*)wr;
      bf16x8 b1 = *(const bf16x8*)(wr + 32);
      acc[nt] = __builtin_amdgcn_mfma_f32_16x16x32_bf16(a0, b0, acc[nt], 0, 0, 0);
      acc[nt] = __builtin_amdgcn_mfma_f32_16x16x32_bf16(a1, b1, acc[nt], 0, 0, 0);
    }
    __syncthreads();
  }

  // epilogue: bias, transpose via LDS (stride 68, 16B aligned), coalesced
  // stores + fused BN partial sums
  #pragma unroll
  for (int nt = 0; nt < 4; ++nt) {
    float4 v;
    v.x = acc[nt][0] + bdv[nt];
    v.y = acc[nt][1] + bdv[nt];
    v.z = acc[nt][2] + bdv[nt];
    v.w = acc[nt][3] + bdv[nt];
    *(float4*)&lds_f[(nt * 16 + m) * 68 + wave * 16 + hi * 4] = v;
  }
  __syncthreads();

  {
    int o = tid >> 2, part = tid & 3;
    const float* rb = lds_f + o * 68 + part * 16;
    float* op = out + ((size_t)(b * 64 + o)) * HW + pbase + part * 16;
    float s = 0.f, ss = 0.f;
    #pragma unroll
    for (int j = 0; j < 4; ++j) {
      float4 v = *(const float4*)&rb[4 * j];
      s += v.x + v.y + v.z + v.w;
      ss += v.x * v.x + v.y * v.y + v.z * v.z + v.w * v.w;
      *(float4*)&op[4 * j] = v;
    }
    red[tid] = s;
    red[256 + tid] = ss;
  }
  __syncthreads();
  if (tid < 64) {
    float rs = red[4 * tid] + red[4 * tid + 1] + red[4 * tid + 2] + red[4 * tid + 3];
    float rq = red[256 + 4 * tid] + red[256 + 4 * tid + 1] +
               red[256 + 4 * tid + 2] + red[256 + 4 * tid + 3];
    parts[(size_t)tid * 1152 + blk] = rs;
    parts[73728 + (size_t)tid * 1152 + blk] = rq;
  }
}

// ---------------------------------------------------------------------------
// K3: finalize BN scale/shift.  64 blocks (one per channel) x 256 threads.
// ---------------------------------------------------------------------------
__global__ __launch_bounds__(256) void k_stats(
    const float* __restrict__ parts, const float* __restrict__ gamma,
    const float* __restrict__ beta, float* __restrict__ stats)
{
  int c = blockIdx.x;
  int tid = threadIdx.x;
  float s = 0.f, ss = 0.f;
  for (int i = tid; i < 1152; i += 256) {
    s += parts[(size_t)c * 1152 + i];
    ss += parts[73728 + (size_t)c * 1152 + i];
  }
  #pragma unroll
  for (int off = 32; off >= 1; off >>= 1) {
    s += __shfl_down(s, off);
    ss += __shfl_down(ss, off);
  }
  __shared__ float rs[4], rss[4];
  int wave = tid >> 6, lane = tid & 63;
  if (lane == 0) { rs[wave] = s; rss[wave] = ss; }
  __syncthreads();
  if (tid == 0) {
    float S1 = rs[0] + rs[1] + rs[2] + rs[3];
    float S2 = rss[0] + rss[1] + rss[2] + rss[3];
    const float inv = 1.f / 73728.f;
    float mean = S1 * inv;
    float var = S2 * inv - mean * mean;
    float scale = gamma[c] * rsqrtf(var + 1e-5f);
    stats[c] = scale;
    stats[64 + c] = beta[c] - mean * scale;
  }
}

// ---------------------------------------------------------------------------
// K4: in-place normalize + affine + relu, float4 vectorized.
// ---------------------------------------------------------------------------
__global__ __launch_bounds__(256) void k_norm(
    float* __restrict__ out, const float* __restrict__ stats)
{
  int g = blockIdx.x * 256 + threadIdx.x;   // over 1179648 float4
  int o = (g / 2304) & 63;                  // 2304 float4 per plane
  float sc = stats[o], sh = stats[64 + o];
  float4 v = ((const float4*)out)[g];
  v.x = fmaxf(fmaf(v.x, sc, sh), 0.f);
  v.y = fmaxf(fmaf(v.y, sc, sh), 0.f);
  v.z = fmaxf(fmaf(v.z, sc, sh), 0.f);
  v.w = fmaxf(fmaf(v.w, sc, sh), 0.f);
  ((float4*)out)[g] = v;
}

extern "C" void kernel_launch(void* const* d_in, const int* in_sizes, int n_in,
                              void* d_out, int out_size, void* d_ws, size_t ws_size,
                              hipStream_t stream) {
  const float* x     = (const float*)d_in[0];
  const float* w_off = (const float*)d_in[1];
  const float* b_off = (const float*)d_in[2];
  const float* w_def = (const float*)d_in[3];
  const float* b_def = (const float*)d_in[4];
  const float* gamma = (const float*)d_in[5];
  const float* beta  = (const float*)d_in[6];
  float* out = (float*)d_out;

  float* offs   = (float*)d_ws;             // 1327104 floats
  ushort* wtb   = (ushort*)(offs + 1327104);  // 36864 bf16 (18432 float slots)
  float* parts  = offs + 1327104 + 18432;   // 2 * 73728 floats
  float* stats  = parts + 2 * 73728;        // 128 floats

  k_offset<<<1152, 256, 0, stream>>>(x, w_off, b_off, w_def, offs, wtb);
  k_deform<<<1152, 256, 0, stream>>>(x, offs, wtb, b_def, out, parts);
  k_stats<<<64, 256, 0, stream>>>(parts, gamma, beta, stats);
  k_norm<<<4608, 256, 0, stream>>>(out, stats);
}

// Round 3
// 193.312 us; speedup vs baseline: 1.5144x; 1.5144x over previous
//
#include <hip/hip_runtime.h>

#define Hh 96
#define Ww 96
#define CIN 64
#define COUT 64
#define BATCH 8
#define HW 9216           // Hh*Ww
#define NOFF 18           // 2*K*K

typedef __attribute__((ext_vector_type(8))) short bf16x8;
typedef __attribute__((ext_vector_type(4))) float f32x4;

__device__ inline ushort f2bf(float f) {
  union { float f; uint u; } v; v.f = f;
  uint u = v.u;
  u += 0x7FFF + ((u >> 16) & 1);     // RNE
  return (ushort)(u >> 16);
}

// ---------------------------------------------------------------------------
// K1: offset conv (18 channels, 3x3, pad 1) + fold w_def -> bf16 [k][o][c].
// ---------------------------------------------------------------------------
__global__ __launch_bounds__(256) void k_offset(
    const float* __restrict__ x, const float* __restrict__ w_off,
    const float* __restrict__ b_off, const float* __restrict__ w_def,
    float* __restrict__ offs, ushort* __restrict__ wtb)
{
  __shared__ float wl[CIN * 9 * 20];       // [c][kk][j padded to 20]
  __shared__ float red[3 * NOFF * 64];

  int tid = threadIdx.x;
  int bid = blockIdx.x;
  int blk = (bid & 7) * 144 + (bid >> 3);   // XCD-batch swizzle (1152 = 8*144)

  // one-time transpose w_def[o][c][k] -> wtb[k][o][c] (bf16)
  if (blk < 144) {
    int g = blk * 256 + tid;
    int k = g >> 12, o = (g >> 6) & 63, c = g & 63;
    wtb[g] = f2bf(w_def[(o * 64 + c) * 9 + k]);
  }

  for (int i = tid; i < NOFF * CIN * 9; i += 256) {
    int j = i / 576;
    int rem = i - j * 576;
    int c = rem / 9;
    int kk = rem - c * 9;
    wl[(c * 9 + kk) * 20 + j] = w_off[i];
  }
  __syncthreads();

  int wave = tid >> 6, lane = tid & 63;
  int p = blk * 64 + lane;
  int b = p / HW;
  int pp = p - b * HW;
  int h = pp / Ww;
  int w = pp - h * Ww;

  float acc[NOFF];
  #pragma unroll
  for (int j = 0; j < NOFF; ++j) acc[j] = 0.f;

  int woff[9];
  float okf[9];
  #pragma unroll
  for (int kk = 0; kk < 9; ++kk) {
    int yy = h + kk / 3 - 1, xx = w + (kk % 3) - 1;
    bool ok = (yy >= 0 && yy < Hh && xx >= 0 && xx < Ww);
    int yc = min(max(yy, 0), Hh - 1), xc = min(max(xx, 0), Ww - 1);
    woff[kk] = yc * Ww + xc;
    okf[kk] = ok ? 1.f : 0.f;
  }

  const float* xb = x + (size_t)(b * CIN + wave * 16) * HW;
  for (int ci = 0; ci < 16; ++ci) {
    const float* xc = xb + ci * HW;
    int c = wave * 16 + ci;
    float xv[9];
    #pragma unroll
    for (int kk = 0; kk < 9; ++kk) xv[kk] = xc[woff[kk]] * okf[kk];
    const float* wr = &wl[c * 180];
    #pragma unroll
    for (int kk = 0; kk < 9; ++kk) {
      const float* wj = wr + kk * 20;
      #pragma unroll
      for (int j = 0; j < NOFF; ++j)
        acc[j] = fmaf(xv[kk], wj[j], acc[j]);
    }
  }

  if (wave > 0) {
    #pragma unroll
    for (int j = 0; j < NOFF; ++j)
      red[(wave - 1) * NOFF * 64 + j * 64 + lane] = acc[j];
  }
  __syncthreads();
  if (wave == 0) {
    #pragma unroll
    for (int j = 0; j < NOFF; ++j) {
      float a = acc[j] + red[j * 64 + lane] + red[1152 + j * 64 + lane] +
                red[2304 + j * 64 + lane];
      offs[((size_t)b * NOFF + j) * HW + pp] = a + b_off[j];
    }
  }
}

// ---------------------------------------------------------------------------
// K2: deformable sampling + MFMA, barrier-free main loop.
// Block = 256 threads (4 waves), 64 pixels x 64 outputs; wave w owns pixels
// [pbase+16w, pbase+16w+16).  Lane (hi,m): gathers channels {hi*8+j} and
// {32+hi*8+j} for pixel m -> A-fragment directly in registers.  B-fragments
// read straight from global wtb[k][o][c] (8KB/tap, L2-broadcast).  No LDS, no
// __syncthreads until the epilogue transpose.
// MFMA mapping (verified r2): A lane(hi,m) = A[i=m][k=hi*8+j];
// B lane(hi,m) = B[k=hi*8+j][n=nt*16+m]; D lane(hi,m) reg r = D[i=hi*4+r][n].
// ---------------------------------------------------------------------------
__global__ __launch_bounds__(256) void k_deform(
    const float* __restrict__ x, const float* __restrict__ offs,
    const ushort* __restrict__ wtb, const float* __restrict__ b_def,
    float* __restrict__ out, float* __restrict__ parts)
{
  __shared__ float lds_f[64 * 68];   // epilogue transpose: [o][p] stride 68
  __shared__ float red[512];

  int tid = threadIdx.x;
  int bid = blockIdx.x;
  int blk = (bid & 7) * 144 + (bid >> 3);   // XCD-batch swizzle: batch = XCD
  int b = blk / 144;
  int pbase = (blk - b * 144) * 64;
  int wave = tid >> 6, lane = tid & 63;
  int m = lane & 15, hi = lane >> 4;
  int p_pix = pbase + wave * 16 + m;        // this lane's pixel
  int h = p_pix / Ww, w = p_pix - (p_pix / Ww) * Ww;

  const float* xb = x + (size_t)b * CIN * HW;      // uniform base

  // per-lane channel element-offsets (hoisted out of k loop)
  int cofs[16];
  #pragma unroll
  for (int j = 0; j < 8; ++j) {
    cofs[j] = (hi * 8 + j) * HW;
    cofs[8 + j] = (32 + hi * 8 + j) * HW;
  }

  // preload offsets for all 9 taps
  float dyv[9], dxv[9];
  {
    const float* ob = offs + (size_t)b * NOFF * HW + p_pix;
    #pragma unroll
    for (int k = 0; k < 9; ++k) {
      dyv[k] = ob[(size_t)(2 * k) * HW];
      dxv[k] = ob[(size_t)(2 * k + 1) * HW];
    }
  }

  f32x4 acc[4];
  #pragma unroll
  for (int nt = 0; nt < 4; ++nt) acc[nt] = (f32x4){0.f, 0.f, 0.f, 0.f};

  #pragma unroll 3
  for (int k = 0; k < 9; ++k) {
    float py = (float)(h + k / 3 - 1) + dyv[k];
    float px = (float)(w + (k - (k / 3) * 3) - 1) + dxv[k];
    float y0f = floorf(py), x0f = floorf(px);
    float ly = py - y0f, lx = px - x0f;
    int y0 = (int)y0f, x0 = (int)x0f;
    int y1 = y0 + 1, x1 = x0 + 1;
    float fy0 = (y0 >= 0 && y0 < Hh) ? 1.f : 0.f;
    float fy1 = (y1 >= 0 && y1 < Hh) ? 1.f : 0.f;
    float fx0 = (x0 >= 0 && x0 < Ww) ? 1.f : 0.f;
    float fx1 = (x1 >= 0 && x1 < Ww) ? 1.f : 0.f;
    int cy0 = min(max(y0, 0), Hh - 1), cy1 = min(max(y1, 0), Hh - 1);
    int cx0 = min(max(x0, 0), Ww - 1), cx1 = min(max(x1, 0), Ww - 1);
    int o00 = cy0 * Ww + cx0, o01 = cy0 * Ww + cx1;
    int o10 = cy1 * Ww + cx0, o11 = cy1 * Ww + cx1;
    float w00 = (1.f - ly) * (1.f - lx) * (fy0 * fx0);
    float w01 = (1.f - ly) * lx * (fy0 * fx1);
    float w10 = ly * (1.f - lx) * (fy1 * fx0);
    float w11 = ly * lx * (fy1 * fx1);

    // issue all 64 gathers first (max MLP)
    float g00[16], g01[16], g10[16], g11[16];
    #pragma unroll
    for (int j = 0; j < 16; ++j) {
      const float* xc = xb + cofs[j];
      g00[j] = xc[o00];
      g01[j] = xc[o01];
      g10[j] = xc[o10];
      g11[j] = xc[o11];
    }

    // B-fragments straight from global (uniform base, coalesced 2KB/nt)
    const ushort* wk = wtb + (size_t)k * 4096 + hi * 8;
    bf16x8 bf[4][2];
    #pragma unroll
    for (int nt = 0; nt < 4; ++nt) {
      bf[nt][0] = *(const bf16x8*)(wk + (nt * 16 + m) * 64);
      bf[nt][1] = *(const bf16x8*)(wk + (nt * 16 + m) * 64 + 32);
    }

    bf16x8 a0, a1;
    #pragma unroll
    for (int j = 0; j < 8; ++j) {
      float v0 = fmaf(w11, g11[j], fmaf(w10, g10[j], fmaf(w01, g01[j], w00 * g00[j])));
      float v1 = fmaf(w11, g11[8 + j], fmaf(w10, g10[8 + j], fmaf(w01, g01[8 + j], w00 * g00[8 + j])));
      a0[j] = (short)f2bf(v0);
      a1[j] = (short)f2bf(v1);
    }

    #pragma unroll
    for (int nt = 0; nt < 4; ++nt) {
      acc[nt] = __builtin_amdgcn_mfma_f32_16x16x32_bf16(a0, bf[nt][0], acc[nt], 0, 0, 0);
      acc[nt] = __builtin_amdgcn_mfma_f32_16x16x32_bf16(a1, bf[nt][1], acc[nt], 0, 0, 0);
    }
  }

  // epilogue: bias, LDS transpose, coalesced stores + fused BN partial sums
  #pragma unroll
  for (int nt = 0; nt < 4; ++nt) {
    float bo = b_def[nt * 16 + m];
    float4 v;
    v.x = acc[nt][0] + bo;
    v.y = acc[nt][1] + bo;
    v.z = acc[nt][2] + bo;
    v.w = acc[nt][3] + bo;
    *(float4*)&lds_f[(nt * 16 + m) * 68 + wave * 16 + hi * 4] = v;
  }
  __syncthreads();

  {
    int o = tid >> 2, part = tid & 3;
    const float* rb = lds_f + o * 68 + part * 16;
    float* op = out + ((size_t)(b * 64 + o)) * HW + pbase + part * 16;
    float s = 0.f, ss = 0.f;
    #pragma unroll
    for (int j = 0; j < 4; ++j) {
      float4 v = *(const float4*)&rb[4 * j];
      s += v.x + v.y + v.z + v.w;
      ss += v.x * v.x + v.y * v.y + v.z * v.z + v.w * v.w;
      *(float4*)&op[4 * j] = v;
    }
    red[tid] = s;
    red[256 + tid] = ss;
  }
  __syncthreads();
  if (tid < 64) {
    float rs = red[4 * tid] + red[4 * tid + 1] + red[4 * tid + 2] + red[4 * tid + 3];
    float rq = red[256 + 4 * tid] + red[256 + 4 * tid + 1] +
               red[256 + 4 * tid + 2] + red[256 + 4 * tid + 3];
    parts[(size_t)tid * 1152 + blk] = rs;
    parts[73728 + (size_t)tid * 1152 + blk] = rq;
  }
}

// ---------------------------------------------------------------------------
// K3: finalize BN scale/shift.  64 blocks (one per channel) x 256 threads.
// ---------------------------------------------------------------------------
__global__ __launch_bounds__(256) void k_stats(
    const float* __restrict__ parts, const float* __restrict__ gamma,
    const float* __restrict__ beta, float* __restrict__ stats)
{
  int c = blockIdx.x;
  int tid = threadIdx.x;
  float s = 0.f, ss = 0.f;
  for (int i = tid; i < 1152; i += 256) {
    s += parts[(size_t)c * 1152 + i];
    ss += parts[73728 + (size_t)c * 1152 + i];
  }
  #pragma unroll
  for (int off = 32; off >= 1; off >>= 1) {
    s += __shfl_down(s, off);
    ss += __shfl_down(ss, off);
  }
  __shared__ float rs[4], rss[4];
  int wave = tid >> 6, lane = tid & 63;
  if (lane == 0) { rs[wave] = s; rss[wave] = ss; }
  __syncthreads();
  if (tid == 0) {
    float S1 = rs[0] + rs[1] + rs[2] + rs[3];
    float S2 = rss[0] + rss[1] + rss[2] + rss[3];
    const float inv = 1.f / 73728.f;
    float mean = S1 * inv;
    float var = S2 * inv - mean * mean;
    float scale = gamma[c] * rsqrtf(var + 1e-5f);
    stats[c] = scale;
    stats[64 + c] = beta[c] - mean * scale;
  }
}

// ---------------------------------------------------------------------------
// K4: in-place normalize + affine + relu, float4 vectorized.
// ---------------------------------------------------------------------------
__global__ __launch_bounds__(256) void k_norm(
    float* __restrict__ out, const float* __restrict__ stats)
{
  int g = blockIdx.x * 256 + threadIdx.x;   // over 1179648 float4
  int o = (g / 2304) & 63;                  // 2304 float4 per plane
  float sc = stats[o], sh = stats[64 + o];
  float4 v = ((const float4*)out)[g];
  v.x = fmaxf(fmaf(v.x, sc, sh), 0.f);
  v.y = fmaxf(fmaf(v.y, sc, sh), 0.f);
  v.z = fmaxf(fmaf(v.z, sc, sh), 0.f);
  v.w = fmaxf(fmaf(v.w, sc, sh), 0.f);
  ((float4*)out)[g] = v;
}

extern "C" void kernel_launch(void* const* d_in, const int* in_sizes, int n_in,
                              void* d_out, int out_size, void* d_ws, size_t ws_size,
                              hipStream_t stream) {
  const float* x     = (const float*)d_in[0];
  const float* w_off = (const float*)d_in[1];
  const float* b_off = (const float*)d_in[2];
  const float* w_def = (const float*)d_in[3];
  const float* b_def = (const float*)d_in[4];
  const float* gamma = (const float*)d_in[5];
  const float* beta  = (const float*)d_in[6];
  float* out = (float*)d_out;

  float* offs   = (float*)d_ws;               // 1327104 floats
  ushort* wtb   = (ushort*)(offs + 1327104);  // 36864 bf16
  float* parts  = offs + 1327104 + 18432;     // 2 * 73728 floats
  float* stats  = parts + 2 * 73728;          // 128 floats

  k_offset<<<1152, 256, 0, stream>>>(x, w_off, b_off, w_def, offs, wtb);
  k_deform<<<1152, 256, 0, stream>>>(x, offs, wtb, b_def, out, parts);
  k_stats<<<64, 256, 0, stream>>>(parts, gamma, beta, stats);
  k_norm<<<4608, 256, 0, stream>>>(out, stats);
}

// Round 4
// 137.432 us; speedup vs baseline: 2.1301x; 1.4066x over previous
//
#include <hip/hip_runtime.h>

#define Hh 96
#define Ww 96
#define CIN 64
#define COUT 64
#define BATCH 8
#define HW 9216           // Hh*Ww
#define NOFF 18           // 2*K*K

typedef __attribute__((ext_vector_type(8))) short bf16x8;
typedef __attribute__((ext_vector_type(4))) float f32x4;

__device__ inline ushort f2bf(float f) {
  union { float f; uint u; } v; v.f = f;
  uint u = v.u;
  u += 0x7FFF + ((u >> 16) & 1);     // RNE
  return (ushort)(u >> 16);
}
__device__ inline float bflo(uint u) {       // low bf16 -> f32
  union { uint u; float f; } v; v.u = u << 16; return v.f;
}
__device__ inline float bfhi(uint u) {       // high bf16 -> f32
  union { uint u; float f; } v; v.u = u & 0xFFFF0000u; return v.f;
}
__device__ inline uint pack_rne(float a, float b) {  // {bf(a), bf(b)} -> u32
  union { float f; uint u; } x, y; x.f = a; y.f = b;
  uint ua = x.u + (0x7FFFu + ((x.u >> 16) & 1));
  uint ub = y.u + (0x7FFFu + ((y.u >> 16) & 1));
  return (ua >> 16) | (ub & 0xFFFF0000u);
}

// ---------------------------------------------------------------------------
// K0: transpose x (NCHW f32) -> xt (NHWC bf16), + pack weights in low blocks.
// Grid 1152; block covers 64 pixels of one batch. lane = channel.
// ---------------------------------------------------------------------------
__global__ __launch_bounds__(256) void k_xt(
    const float* __restrict__ x, const float* __restrict__ w_def,
    const float* __restrict__ w_off, ushort* __restrict__ xt,
    ushort* __restrict__ wtb, ushort* __restrict__ wob)
{
  int tid = threadIdx.x;
  int blk = blockIdx.x;

  // fold weight packing into low blocks
  if (blk < 9) {            // wtb[k][o][c] = bf16(w_def[o][c][k]), k = blk
    for (int i = tid; i < 4096; i += 256) {
      int o = i >> 6, c = i & 63;
      wtb[blk * 4096 + i] = f2bf(w_def[(o * 64 + c) * 9 + blk]);
    }
  } else if (blk < 25 && blk >= 16) {   // wob[k][n(32)][c], k = blk-16
    int k = blk - 16;
    for (int i = tid; i < 2048; i += 256) {
      int n = i >> 6, c = i & 63;
      wob[k * 2048 + i] = (n < NOFF) ? f2bf(w_off[(n * 64 + c) * 9 + k]) : (ushort)0;
    }
  }

  int b = blk / 144;
  int pbase = (blk - b * 144) * 64;
  int wave = tid >> 6, c = tid & 63;
  const float* xp = x + ((size_t)b * CIN + c) * HW;
  ushort* xtp = xt + ((size_t)b * HW) * 64 + c;
  #pragma unroll
  for (int i = 0; i < 16; ++i) {
    int p = pbase + wave * 16 + i;
    xtp[(size_t)p * 64] = f2bf(xp[p]);
  }
}

// ---------------------------------------------------------------------------
// K1: offset conv via MFMA on NHWC bf16.  Block = 64 px, 4 waves; wave owns
// 16 px; lane(hi,m) = pixel m, channels {hi*8+j} / {32+hi*8+j}.
// Integer taps, zero-padded via validity.  N = 32 (18 real + 14 pad).
// ---------------------------------------------------------------------------
__global__ __launch_bounds__(256) void k_offs(
    const ushort* __restrict__ xt, const ushort* __restrict__ wob,
    const float* __restrict__ b_off, float* __restrict__ offs)
{
  int tid = threadIdx.x;
  int bid = blockIdx.x;
  int blk = (bid & 7) * 144 + (bid >> 3);   // XCD-batch swizzle
  int b = blk / 144;
  int pbase = (blk - b * 144) * 64;
  int wave = tid >> 6, lane = tid & 63;
  int m = lane & 15, hi = lane >> 4;
  int p_pix = pbase + wave * 16 + m;
  int h = p_pix / Ww, w = p_pix - (p_pix / Ww) * Ww;

  const ushort* xb = xt + ((size_t)b * HW) * 64;

  f32x4 acc[2];
  acc[0] = (f32x4){0.f, 0.f, 0.f, 0.f};
  acc[1] = (f32x4){0.f, 0.f, 0.f, 0.f};

  #pragma unroll 3
  for (int k = 0; k < 9; ++k) {
    int ky = k / 3, kx = k - ky * 3;
    int yy = h + ky - 1, xx = w + kx - 1;
    bool valid = (yy >= 0 && yy < Hh && xx >= 0 && xx < Ww);
    int pos = min(max(yy, 0), Hh - 1) * Ww + min(max(xx, 0), Ww - 1);
    const ushort* pp = xb + (size_t)pos * 64 + hi * 8;
    bf16x8 a0 = *(const bf16x8*)pp;
    bf16x8 a1 = *(const bf16x8*)(pp + 32);
    if (!valid) { a0 = (bf16x8)0; a1 = (bf16x8)0; }

    const ushort* wk = wob + (size_t)k * 2048 + hi * 8;
    #pragma unroll
    for (int nt = 0; nt < 2; ++nt) {
      bf16x8 b0 = *(const bf16x8*)(wk + (nt * 16 + m) * 64);
      bf16x8 b1 = *(const bf16x8*)(wk + (nt * 16 + m) * 64 + 32);
      acc[nt] = __builtin_amdgcn_mfma_f32_16x16x32_bf16(a0, b0, acc[nt], 0, 0, 0);
      acc[nt] = __builtin_amdgcn_mfma_f32_16x16x32_bf16(a1, b1, acc[nt], 0, 0, 0);
    }
  }

  // D lane(hi,m) reg r -> offset-ch j = nt*16+m, pixel pbase+wave*16+hi*4+r
  #pragma unroll
  for (int nt = 0; nt < 2; ++nt) {
    int j = nt * 16 + m;
    if (j < NOFF) {
      float bo = b_off[j];
      float4 v;
      v.x = acc[nt][0] + bo;
      v.y = acc[nt][1] + bo;
      v.z = acc[nt][2] + bo;
      v.w = acc[nt][3] + bo;
      *(float4*)&offs[((size_t)b * NOFF + j) * HW + pbase + wave * 16 + hi * 4] = v;
    }
  }
}

// ---------------------------------------------------------------------------
// K2: deformable sampling from NHWC bf16 + MFMA, barrier-free main loop.
// 8 x dwordx4 gathers per lane per tap (4 corners x 2 channel-halves).
// ---------------------------------------------------------------------------
__global__ __launch_bounds__(256) void k_deform(
    const ushort* __restrict__ xt, const float* __restrict__ offs,
    const ushort* __restrict__ wtb, const float* __restrict__ b_def,
    float* __restrict__ out, float* __restrict__ parts)
{
  __shared__ float lds_f[64 * 68];   // epilogue transpose: [o][p] stride 68
  __shared__ float red[512];

  int tid = threadIdx.x;
  int bid = blockIdx.x;
  int blk = (bid & 7) * 144 + (bid >> 3);   // XCD-batch swizzle: batch = XCD
  int b = blk / 144;
  int pbase = (blk - b * 144) * 64;
  int wave = tid >> 6, lane = tid & 63;
  int m = lane & 15, hi = lane >> 4;
  int p_pix = pbase + wave * 16 + m;
  int h = p_pix / Ww, w = p_pix - (p_pix / Ww) * Ww;

  const ushort* xb = xt + ((size_t)b * HW) * 64;
  const float* ob = offs + (size_t)b * NOFF * HW + p_pix;

  f32x4 acc[4];
  #pragma unroll
  for (int nt = 0; nt < 4; ++nt) acc[nt] = (f32x4){0.f, 0.f, 0.f, 0.f};

  #pragma unroll 2
  for (int k = 0; k < 9; ++k) {
    float dy = ob[(size_t)(2 * k) * HW];
    float dx = ob[(size_t)(2 * k + 1) * HW];
    int ky = k / 3, kx = k - ky * 3;
    float py = (float)(h + ky - 1) + dy;
    float px = (float)(w + kx - 1) + dx;
    float y0f = floorf(py), x0f = floorf(px);
    float ly = py - y0f, lx = px - x0f;
    int y0 = (int)y0f, x0 = (int)x0f;
    int y1 = y0 + 1, x1 = x0 + 1;
    float fy0 = (y0 >= 0 && y0 < Hh) ? 1.f : 0.f;
    float fy1 = (y1 >= 0 && y1 < Hh) ? 1.f : 0.f;
    float fx0 = (x0 >= 0 && x0 < Ww) ? 1.f : 0.f;
    float fx1 = (x1 >= 0 && x1 < Ww) ? 1.f : 0.f;
    int cy0 = min(max(y0, 0), Hh - 1), cy1 = min(max(y1, 0), Hh - 1);
    int cx0 = min(max(x0, 0), Ww - 1), cx1 = min(max(x1, 0), Ww - 1);
    size_t o00 = (size_t)(cy0 * Ww + cx0) * 64;
    size_t o01 = (size_t)(cy0 * Ww + cx1) * 64;
    size_t o10 = (size_t)(cy1 * Ww + cx0) * 64;
    size_t o11 = (size_t)(cy1 * Ww + cx1) * 64;
    float w00 = (1.f - ly) * (1.f - lx) * (fy0 * fx0);
    float w01 = (1.f - ly) * lx * (fy0 * fx1);
    float w10 = ly * (1.f - lx) * (fy1 * fx0);
    float w11 = ly * lx * (fy1 * fx1);

    // 8 gathers of 16B: 4 corners x {a0 chans hi*8.., a1 chans 32+hi*8..}
    const ushort* pa = xb + hi * 8;
    uint4 c00a = *(const uint4*)(pa + o00), c00b = *(const uint4*)(pa + o00 + 32);
    uint4 c01a = *(const uint4*)(pa + o01), c01b = *(const uint4*)(pa + o01 + 32);
    uint4 c10a = *(const uint4*)(pa + o10), c10b = *(const uint4*)(pa + o10 + 32);
    uint4 c11a = *(const uint4*)(pa + o11), c11b = *(const uint4*)(pa + o11 + 32);

    // B-fragments straight from global (L1/L2-resident, 8KB/tap)
    const ushort* wk = wtb + (size_t)k * 4096 + hi * 8;
    uint4 bfr[4][2];
    #pragma unroll
    for (int nt = 0; nt < 4; ++nt) {
      bfr[nt][0] = *(const uint4*)(wk + (nt * 16 + m) * 64);
      bfr[nt][1] = *(const uint4*)(wk + (nt * 16 + m) * 64 + 32);
    }

    // interpolate pairwise, repack to bf16
    uint4 ua, ub;
    {
      uint* pc00 = (uint*)&c00a; uint* pc01 = (uint*)&c01a;
      uint* pc10 = (uint*)&c10a; uint* pc11 = (uint*)&c11a;
      uint* dst = (uint*)&ua;
      #pragma unroll
      for (int q = 0; q < 4; ++q) {
        float vlo = fmaf(w11, bflo(pc11[q]), fmaf(w10, bflo(pc10[q]),
                    fmaf(w01, bflo(pc01[q]), w00 * bflo(pc00[q]))));
        float vhi = fmaf(w11, bfhi(pc11[q]), fmaf(w10, bfhi(pc10[q]),
                    fmaf(w01, bfhi(pc01[q]), w00 * bfhi(pc00[q]))));
        dst[q] = pack_rne(vlo, vhi);
      }
      pc00 = (uint*)&c00b; pc01 = (uint*)&c01b;
      pc10 = (uint*)&c10b; pc11 = (uint*)&c11b;
      dst = (uint*)&ub;
      #pragma unroll
      for (int q = 0; q < 4; ++q) {
        float vlo = fmaf(w11, bflo(pc11[q]), fmaf(w10, bflo(pc10[q]),
                    fmaf(w01, bflo(pc01[q]), w00 * bflo(pc00[q]))));
        float vhi = fmaf(w11, bfhi(pc11[q]), fmaf(w10, bfhi(pc10[q]),
                    fmaf(w01, bfhi(pc01[q]), w00 * bfhi(pc00[q]))));
        dst[q] = pack_rne(vlo, vhi);
      }
    }
    bf16x8 a0, a1;
    __builtin_memcpy(&a0, &ua, 16);
    __builtin_memcpy(&a1, &ub, 16);

    #pragma unroll
    for (int nt = 0; nt < 4; ++nt) {
      bf16x8 b0, b1;
      __builtin_memcpy(&b0, &bfr[nt][0], 16);
      __builtin_memcpy(&b1, &bfr[nt][1], 16);
      acc[nt] = __builtin_amdgcn_mfma_f32_16x16x32_bf16(a0, b0, acc[nt], 0, 0, 0);
      acc[nt] = __builtin_amdgcn_mfma_f32_16x16x32_bf16(a1, b1, acc[nt], 0, 0, 0);
    }
  }

  // epilogue: bias, LDS transpose, coalesced stores + fused BN partial sums
  #pragma unroll
  for (int nt = 0; nt < 4; ++nt) {
    float bo = b_def[nt * 16 + m];
    float4 v;
    v.x = acc[nt][0] + bo;
    v.y = acc[nt][1] + bo;
    v.z = acc[nt][2] + bo;
    v.w = acc[nt][3] + bo;
    *(float4*)&lds_f[(nt * 16 + m) * 68 + wave * 16 + hi * 4] = v;
  }
  __syncthreads();

  {
    int o = tid >> 2, part = tid & 3;
    const float* rb = lds_f + o * 68 + part * 16;
    float* op = out + ((size_t)(b * 64 + o)) * HW + pbase + part * 16;
    float s = 0.f, ss = 0.f;
    #pragma unroll
    for (int j = 0; j < 4; ++j) {
      float4 v = *(const float4*)&rb[4 * j];
      s += v.x + v.y + v.z + v.w;
      ss += v.x * v.x + v.y * v.y + v.z * v.z + v.w * v.w;
      *(float4*)&op[4 * j] = v;
    }
    red[tid] = s;
    red[256 + tid] = ss;
  }
  __syncthreads();
  if (tid < 64) {
    float rs = red[4 * tid] + red[4 * tid + 1] + red[4 * tid + 2] + red[4 * tid + 3];
    float rq = red[256 + 4 * tid] + red[256 + 4 * tid + 1] +
               red[256 + 4 * tid + 2] + red[256 + 4 * tid + 3];
    parts[(size_t)tid * 1152 + blk] = rs;
    parts[73728 + (size_t)tid * 1152 + blk] = rq;
  }
}

// ---------------------------------------------------------------------------
// K3: finalize BN scale/shift.  64 blocks x 256 threads.
// ---------------------------------------------------------------------------
__global__ __launch_bounds__(256) void k_stats(
    const float* __restrict__ parts, const float* __restrict__ gamma,
    const float* __restrict__ beta, float* __restrict__ stats)
{
  int c = blockIdx.x;
  int tid = threadIdx.x;
  float s = 0.f, ss = 0.f;
  for (int i = tid; i < 1152; i += 256) {
    s += parts[(size_t)c * 1152 + i];
    ss += parts[73728 + (size_t)c * 1152 + i];
  }
  #pragma unroll
  for (int off = 32; off >= 1; off >>= 1) {
    s += __shfl_down(s, off);
    ss += __shfl_down(ss, off);
  }
  __shared__ float rs[4], rss[4];
  int wave = tid >> 6, lane = tid & 63;
  if (lane == 0) { rs[wave] = s; rss[wave] = ss; }
  __syncthreads();
  if (tid == 0) {
    float S1 = rs[0] + rs[1] + rs[2] + rs[3];
    float S2 = rss[0] + rss[1] + rss[2] + rss[3];
    const float inv = 1.f / 73728.f;
    float mean = S1 * inv;
    float var = S2 * inv - mean * mean;
    float scale = gamma[c] * rsqrtf(var + 1e-5f);
    stats[c] = scale;
    stats[64 + c] = beta[c] - mean * scale;
  }
}

// ---------------------------------------------------------------------------
// K4: in-place normalize + affine + relu, float4 vectorized.
// ---------------------------------------------------------------------------
__global__ __launch_bounds__(256) void k_norm(
    float* __restrict__ out, const float* __restrict__ stats)
{
  int g = blockIdx.x * 256 + threadIdx.x;   // over 1179648 float4
  int o = (g / 2304) & 63;                  // 2304 float4 per plane
  float sc = stats[o], sh = stats[64 + o];
  float4 v = ((const float4*)out)[g];
  v.x = fmaxf(fmaf(v.x, sc, sh), 0.f);
  v.y = fmaxf(fmaf(v.y, sc, sh), 0.f);
  v.z = fmaxf(fmaf(v.z, sc, sh), 0.f);
  v.w = fmaxf(fmaf(v.w, sc, sh), 0.f);
  ((float4*)out)[g] = v;
}

extern "C" void kernel_launch(void* const* d_in, const int* in_sizes, int n_in,
                              void* d_out, int out_size, void* d_ws, size_t ws_size,
                              hipStream_t stream) {
  const float* x     = (const float*)d_in[0];
  const float* w_off = (const float*)d_in[1];
  const float* b_off = (const float*)d_in[2];
  const float* w_def = (const float*)d_in[3];
  const float* b_def = (const float*)d_in[4];
  const float* gamma = (const float*)d_in[5];
  const float* beta  = (const float*)d_in[6];
  float* out = (float*)d_out;

  // workspace layout (floats): offs | wtb | wob | xt | parts | stats
  float* offs  = (float*)d_ws;               // 1327104
  ushort* wtb  = (ushort*)(offs + 1327104);  // 36864 bf16 (18432 slots)
  ushort* wob  = (ushort*)(offs + 1327104 + 18432);  // 18432 bf16 (9216 slots)
  ushort* xt   = (ushort*)(offs + 1327104 + 18432 + 9216);  // 4718592 bf16 (2359296 slots)
  float* parts = offs + 1327104 + 18432 + 9216 + 2359296;   // 147456
  float* stats = parts + 147456;             // 128

  k_xt<<<1152, 256, 0, stream>>>(x, w_def, w_off, xt, wtb, wob);
  k_offs<<<1152, 256, 0, stream>>>(xt, wob, b_off, offs);
  k_deform<<<1152, 256, 0, stream>>>(xt, offs, wtb, b_def, out, parts);
  k_stats<<<64, 256, 0, stream>>>(parts, gamma, beta, stats);
  k_norm<<<4608, 256, 0, stream>>>(out, stats);
}

// Round 5
// 134.016 us; speedup vs baseline: 2.1844x; 1.0255x over previous
//
#include <hip/hip_runtime.h>

#define Hh 96
#define Ww 96
#define CIN 64
#define COUT 64
#define BATCH 8
#define HW 9216           // Hh*Ww
#define NOFF 18           // 2*K*K

typedef __attribute__((ext_vector_type(8))) short bf16x8;
typedef __attribute__((ext_vector_type(4))) float f32x4;

__device__ inline ushort f2bf(float f) {
  union { float f; uint u; } v; v.f = f;
  uint u = v.u;
  u += 0x7FFF + ((u >> 16) & 1);     // RNE
  return (ushort)(u >> 16);
}
__device__ inline float bflo(uint u) {       // low bf16 -> f32
  union { uint u; float f; } v; v.u = u << 16; return v.f;
}
__device__ inline float bfhi(uint u) {       // high bf16 -> f32
  union { uint u; float f; } v; v.u = u & 0xFFFF0000u; return v.f;
}
__device__ inline uint pack_rne(float a, float b) {  // {bf(a), bf(b)} -> u32
  union { float f; uint u; } x, y; x.f = a; y.f = b;
  uint ua = x.u + (0x7FFFu + ((x.u >> 16) & 1));
  uint ub = y.u + (0x7FFFu + ((y.u >> 16) & 1));
  return (ua >> 16) | (ub & 0xFFFF0000u);
}

// ---------------------------------------------------------------------------
// K0: transpose x (NCHW f32) -> xt (NHWC bf16) via padded LDS tile (coalesced
// both directions), + pack weights (wtb, wob) in low blocks.
// ---------------------------------------------------------------------------
__global__ __launch_bounds__(256) void k_xt(
    const float* __restrict__ x, const float* __restrict__ w_def,
    const float* __restrict__ w_off, ushort* __restrict__ xt,
    ushort* __restrict__ wtb, ushort* __restrict__ wob)
{
  __shared__ float tile[64][65];
  int tid = threadIdx.x;
  int blk = blockIdx.x;

  if (blk < 9) {            // wtb[k][o][c] = bf16(w_def[o][c][k]), k = blk
    for (int i = tid; i < 4096; i += 256) {
      int o = i >> 6, c = i & 63;
      wtb[blk * 4096 + i] = f2bf(w_def[(o * 64 + c) * 9 + blk]);
    }
  } else if (blk < 25 && blk >= 16) {   // wob[k][n(32)][c], k = blk-16
    int k = blk - 16;
    for (int i = tid; i < 2048; i += 256) {
      int n = i >> 6, c = i & 63;
      wob[k * 2048 + i] = (n < NOFF) ? f2bf(w_off[(n * 64 + c) * 9 + k]) : (ushort)0;
    }
  }

  int b = blk / 144;
  int pbase = (blk - b * 144) * 64;
  int wave = tid >> 6, lane = tid & 63;
  const float* xp = x + (size_t)b * CIN * HW + pbase;
  #pragma unroll
  for (int i = 0; i < 16; ++i) {
    int c = wave * 16 + i;
    tile[lane][c] = xp[(size_t)c * HW + lane];    // coalesced 256B reads
  }
  __syncthreads();
  ushort* xo = xt + ((size_t)b * HW + pbase) * 64;
  #pragma unroll
  for (int i = 0; i < 16; ++i) {
    int p = wave * 16 + i;
    xo[(size_t)p * 64 + lane] = f2bf(tile[p][lane]);  // coalesced 128B writes
  }
}

// gather set + bilinear weights for one tap
struct TapG {
  uint4 c00a, c00b, c01a, c01b, c10a, c10b, c11a, c11b;
  float w00, w01, w10, w11;
};

// ---------------------------------------------------------------------------
// K1: FUSED offset-conv + deformable sampling + MFMA + BN partials.
// Block = 256 threads (4 waves), 64 px x 64 out; wave owns 16 px.
// Phase A: 18-ch offset conv via MFMA (static taps), result exchanged through
//          a per-wave LDS slice (no barrier: wave-private region).
// Phase B: 9-tap deform loop, double-buffered gather pipeline (issue tap k+1
//          while interpolating tap k).  No __syncthreads until epilogue.
// ---------------------------------------------------------------------------
__global__ __launch_bounds__(256, 3) void k_deform(
    const ushort* __restrict__ xt, const ushort* __restrict__ wtb,
    const ushort* __restrict__ wob, const float* __restrict__ b_off,
    const float* __restrict__ b_def, float* __restrict__ out,
    float* __restrict__ parts)
{
  __shared__ float lds_f[64 * 68];       // epilogue transpose
  __shared__ float red[512];
  __shared__ float offs_lds[4][18][17];  // per-wave offset exchange

  int tid = threadIdx.x;
  int bid = blockIdx.x;
  int blk = (bid & 7) * 144 + (bid >> 3);   // XCD-batch swizzle: batch = XCD
  int b = blk / 144;
  int pbase = (blk - b * 144) * 64;
  int wave = tid >> 6, lane = tid & 63;
  int m = lane & 15, hi = lane >> 4;
  int p_pix = pbase + wave * 16 + m;
  int h = p_pix / Ww, w = p_pix - (p_pix / Ww) * Ww;

  const ushort* xb = xt + ((size_t)b * HW) * 64;

  // ---------------- Phase A: offset conv (18 out-ch, static 3x3) -----------
  {
    f32x4 oacc[2];
    oacc[0] = (f32x4){0.f, 0.f, 0.f, 0.f};
    oacc[1] = (f32x4){0.f, 0.f, 0.f, 0.f};

    #pragma unroll
    for (int k = 0; k < 9; ++k) {
      int ky = k / 3, kx = k - ky * 3;
      int yy = h + ky - 1, xx = w + kx - 1;
      bool valid = (yy >= 0 && yy < Hh && xx >= 0 && xx < Ww);
      int pos = min(max(yy, 0), Hh - 1) * Ww + min(max(xx, 0), Ww - 1);
      const ushort* pp = xb + (size_t)pos * 64 + hi * 8;
      bf16x8 a0 = *(const bf16x8*)pp;
      bf16x8 a1 = *(const bf16x8*)(pp + 32);
      if (!valid) { a0 = (bf16x8)0; a1 = (bf16x8)0; }

      const ushort* wk = wob + (size_t)k * 2048 + hi * 8;
      #pragma unroll
      for (int nt = 0; nt < 2; ++nt) {
        bf16x8 b0 = *(const bf16x8*)(wk + (nt * 16 + m) * 64);
        bf16x8 b1 = *(const bf16x8*)(wk + (nt * 16 + m) * 64 + 32);
        oacc[nt] = __builtin_amdgcn_mfma_f32_16x16x32_bf16(a0, b0, oacc[nt], 0, 0, 0);
        oacc[nt] = __builtin_amdgcn_mfma_f32_16x16x32_bf16(a1, b1, oacc[nt], 0, 0, 0);
      }
    }

    // D lane(hi,m) reg r = conv-out[ch j=nt*16+m][px wave*16+hi*4+r]
    #pragma unroll
    for (int nt = 0; nt < 2; ++nt) {
      int j = nt * 16 + m;
      if (j < NOFF) {
        float bo = b_off[j];
        #pragma unroll
        for (int r = 0; r < 4; ++r)
          offs_lds[wave][j][hi * 4 + r] = oacc[nt][r] + bo;
      }
    }
    // no barrier: each wave reads only its own slice below (lgkmcnt orders)
  }

  // ---------------- Phase B: deform loop, 2-tap gather pipeline ------------
  f32x4 acc[4];
  #pragma unroll
  for (int nt = 0; nt < 4; ++nt) acc[nt] = (f32x4){0.f, 0.f, 0.f, 0.f};

  auto tap_issue = [&](int k, TapG& t) {
    float dy = offs_lds[wave][2 * k][m];
    float dx = offs_lds[wave][2 * k + 1][m];
    int ky = k / 3, kx = k - ky * 3;
    float py = (float)(h + ky - 1) + dy;
    float px = (float)(w + kx - 1) + dx;
    float y0f = floorf(py), x0f = floorf(px);
    float ly = py - y0f, lx = px - x0f;
    int y0 = (int)y0f, x0 = (int)x0f;
    int y1 = y0 + 1, x1 = x0 + 1;
    float fy0 = (y0 >= 0 && y0 < Hh) ? 1.f : 0.f;
    float fy1 = (y1 >= 0 && y1 < Hh) ? 1.f : 0.f;
    float fx0 = (x0 >= 0 && x0 < Ww) ? 1.f : 0.f;
    float fx1 = (x1 >= 0 && x1 < Ww) ? 1.f : 0.f;
    int cy0 = min(max(y0, 0), Hh - 1), cy1 = min(max(y1, 0), Hh - 1);
    int cx0 = min(max(x0, 0), Ww - 1), cx1 = min(max(x1, 0), Ww - 1);
    size_t o00 = (size_t)(cy0 * Ww + cx0) * 64;
    size_t o01 = (size_t)(cy0 * Ww + cx1) * 64;
    size_t o10 = (size_t)(cy1 * Ww + cx0) * 64;
    size_t o11 = (size_t)(cy1 * Ww + cx1) * 64;
    t.w00 = (1.f - ly) * (1.f - lx) * (fy0 * fx0);
    t.w01 = (1.f - ly) * lx * (fy0 * fx1);
    t.w10 = ly * (1.f - lx) * (fy1 * fx0);
    t.w11 = ly * lx * (fy1 * fx1);
    const ushort* pa = xb + hi * 8;
    t.c00a = *(const uint4*)(pa + o00); t.c00b = *(const uint4*)(pa + o00 + 32);
    t.c01a = *(const uint4*)(pa + o01); t.c01b = *(const uint4*)(pa + o01 + 32);
    t.c10a = *(const uint4*)(pa + o10); t.c10b = *(const uint4*)(pa + o10 + 32);
    t.c11a = *(const uint4*)(pa + o11); t.c11b = *(const uint4*)(pa + o11 + 32);
  };

  TapG tA, tB;
  tap_issue(0, tA);

  #pragma unroll
  for (int k = 0; k < 9; ++k) {
    TapG& cur = (k & 1) ? tB : tA;
    TapG& nxt = (k & 1) ? tA : tB;
    if (k < 8) tap_issue(k + 1, nxt);   // gathers in flight during interp

    // B-fragments (L1-resident after first iteration)
    const ushort* wk = wtb + (size_t)k * 4096 + hi * 8;
    uint4 bfr[4][2];
    #pragma unroll
    for (int nt = 0; nt < 4; ++nt) {
      bfr[nt][0] = *(const uint4*)(wk + (nt * 16 + m) * 64);
      bfr[nt][1] = *(const uint4*)(wk + (nt * 16 + m) * 64 + 32);
    }

    // interpolate pairwise, repack to bf16
    uint4 ua, ub;
    {
      const uint* pc00 = (const uint*)&cur.c00a;
      const uint* pc01 = (const uint*)&cur.c01a;
      const uint* pc10 = (const uint*)&cur.c10a;
      const uint* pc11 = (const uint*)&cur.c11a;
      uint* dst = (uint*)&ua;
      #pragma unroll
      for (int q = 0; q < 4; ++q) {
        float vlo = fmaf(cur.w11, bflo(pc11[q]), fmaf(cur.w10, bflo(pc10[q]),
                    fmaf(cur.w01, bflo(pc01[q]), cur.w00 * bflo(pc00[q]))));
        float vhi = fmaf(cur.w11, bfhi(pc11[q]), fmaf(cur.w10, bfhi(pc10[q]),
                    fmaf(cur.w01, bfhi(pc01[q]), cur.w00 * bfhi(pc00[q]))));
        dst[q] = pack_rne(vlo, vhi);
      }
      pc00 = (const uint*)&cur.c00b;
      pc01 = (const uint*)&cur.c01b;
      pc10 = (const uint*)&cur.c10b;
      pc11 = (const uint*)&cur.c11b;
      dst = (uint*)&ub;
      #pragma unroll
      for (int q = 0; q < 4; ++q) {
        float vlo = fmaf(cur.w11, bflo(pc11[q]), fmaf(cur.w10, bflo(pc10[q]),
                    fmaf(cur.w01, bflo(pc01[q]), cur.w00 * bflo(pc00[q]))));
        float vhi = fmaf(cur.w11, bfhi(pc11[q]), fmaf(cur.w10, bfhi(pc10[q]),
                    fmaf(cur.w01, bfhi(pc01[q]), cur.w00 * bfhi(pc00[q]))));
        dst[q] = pack_rne(vlo, vhi);
      }
    }
    bf16x8 a0, a1;
    __builtin_memcpy(&a0, &ua, 16);
    __builtin_memcpy(&a1, &ub, 16);

    #pragma unroll
    for (int nt = 0; nt < 4; ++nt) {
      bf16x8 b0, b1;
      __builtin_memcpy(&b0, &bfr[nt][0], 16);
      __builtin_memcpy(&b1, &bfr[nt][1], 16);
      acc[nt] = __builtin_amdgcn_mfma_f32_16x16x32_bf16(a0, b0, acc[nt], 0, 0, 0);
      acc[nt] = __builtin_amdgcn_mfma_f32_16x16x32_bf16(a1, b1, acc[nt], 0, 0, 0);
    }
  }

  // epilogue: bias, LDS transpose, coalesced stores + fused BN partial sums
  #pragma unroll
  for (int nt = 0; nt < 4; ++nt) {
    float bo = b_def[nt * 16 + m];
    float4 v;
    v.x = acc[nt][0] + bo;
    v.y = acc[nt][1] + bo;
    v.z = acc[nt][2] + bo;
    v.w = acc[nt][3] + bo;
    *(float4*)&lds_f[(nt * 16 + m) * 68 + wave * 16 + hi * 4] = v;
  }
  __syncthreads();

  {
    int o = tid >> 2, part = tid & 3;
    const float* rb = lds_f + o * 68 + part * 16;
    float* op = out + ((size_t)(b * 64 + o)) * HW + pbase + part * 16;
    float s = 0.f, ss = 0.f;
    #pragma unroll
    for (int j = 0; j < 4; ++j) {
      float4 v = *(const float4*)&rb[4 * j];
      s += v.x + v.y + v.z + v.w;
      ss += v.x * v.x + v.y * v.y + v.z * v.z + v.w * v.w;
      *(float4*)&op[4 * j] = v;
    }
    red[tid] = s;
    red[256 + tid] = ss;
  }
  __syncthreads();
  if (tid < 64) {
    float rs = red[4 * tid] + red[4 * tid + 1] + red[4 * tid + 2] + red[4 * tid + 3];
    float rq = red[256 + 4 * tid] + red[256 + 4 * tid + 1] +
               red[256 + 4 * tid + 2] + red[256 + 4 * tid + 3];
    parts[(size_t)tid * 1152 + blk] = rs;
    parts[73728 + (size_t)tid * 1152 + blk] = rq;
  }
}

// ---------------------------------------------------------------------------
// K3: finalize BN scale/shift.  64 blocks x 256 threads.
// ---------------------------------------------------------------------------
__global__ __launch_bounds__(256) void k_stats(
    const float* __restrict__ parts, const float* __restrict__ gamma,
    const float* __restrict__ beta, float* __restrict__ stats)
{
  int c = blockIdx.x;
  int tid = threadIdx.x;
  float s = 0.f, ss = 0.f;
  for (int i = tid; i < 1152; i += 256) {
    s += parts[(size_t)c * 1152 + i];
    ss += parts[73728 + (size_t)c * 1152 + i];
  }
  #pragma unroll
  for (int off = 32; off >= 1; off >>= 1) {
    s += __shfl_down(s, off);
    ss += __shfl_down(ss, off);
  }
  __shared__ float rs[4], rss[4];
  int wave = tid >> 6, lane = tid & 63;
  if (lane == 0) { rs[wave] = s; rss[wave] = ss; }
  __syncthreads();
  if (tid == 0) {
    float S1 = rs[0] + rs[1] + rs[2] + rs[3];
    float S2 = rss[0] + rss[1] + rss[2] + rss[3];
    const float inv = 1.f / 73728.f;
    float mean = S1 * inv;
    float var = S2 * inv - mean * mean;
    float scale = gamma[c] * rsqrtf(var + 1e-5f);
    stats[c] = scale;
    stats[64 + c] = beta[c] - mean * scale;
  }
}

// ---------------------------------------------------------------------------
// K4: in-place normalize + affine + relu, float4 vectorized.
// ---------------------------------------------------------------------------
__global__ __launch_bounds__(256) void k_norm(
    float* __restrict__ out, const float* __restrict__ stats)
{
  int g = blockIdx.x * 256 + threadIdx.x;   // over 1179648 float4
  int o = (g / 2304) & 63;                  // 2304 float4 per plane
  float sc = stats[o], sh = stats[64 + o];
  float4 v = ((const float4*)out)[g];
  v.x = fmaxf(fmaf(v.x, sc, sh), 0.f);
  v.y = fmaxf(fmaf(v.y, sc, sh), 0.f);
  v.z = fmaxf(fmaf(v.z, sc, sh), 0.f);
  v.w = fmaxf(fmaf(v.w, sc, sh), 0.f);
  ((float4*)out)[g] = v;
}

extern "C" void kernel_launch(void* const* d_in, const int* in_sizes, int n_in,
                              void* d_out, int out_size, void* d_ws, size_t ws_size,
                              hipStream_t stream) {
  const float* x     = (const float*)d_in[0];
  const float* w_off = (const float*)d_in[1];
  const float* b_off = (const float*)d_in[2];
  const float* w_def = (const float*)d_in[3];
  const float* b_def = (const float*)d_in[4];
  const float* gamma = (const float*)d_in[5];
  const float* beta  = (const float*)d_in[6];
  float* out = (float*)d_out;

  // workspace layout (float slots): wtb | wob | xt | parts | stats
  float* base  = (float*)d_ws;
  ushort* wtb  = (ushort*)base;                    // 36864 bf16 (18432 slots)
  ushort* wob  = (ushort*)(base + 18432);          // 18432 bf16 (9216 slots)
  ushort* xt   = (ushort*)(base + 18432 + 9216);   // 4718592 bf16 (2359296 slots)
  float* parts = base + 18432 + 9216 + 2359296;    // 147456
  float* stats = parts + 147456;                   // 128

  k_xt<<<1152, 256, 0, stream>>>(x, w_def, w_off, xt, wtb, wob);
  k_deform<<<1152, 256, 0, stream>>>(xt, wtb, wob, b_off, b_def, out, parts);
  k_stats<<<64, 256, 0, stream>>>(parts, gamma, beta, stats);
  k_norm<<<4608, 256, 0, stream>>>(out, stats);
}